// Round 1
// baseline (419.802 us; speedup 1.0000x reference)
//
#include <hip/hip_runtime.h>
#include <hip/hip_bf16.h>
#include <math.h>

#define SEQ 2048
#define NHEADS 32
#define NKVH 8
#define HD 128
#define HIDDEN 4096

typedef unsigned short u16;
typedef unsigned int u32;
typedef __attribute__((ext_vector_type(8))) __bf16 bf16x8;
typedef __attribute__((ext_vector_type(4))) float f32x4;
typedef __attribute__((ext_vector_type(4))) u16 u16x4;

__device__ __forceinline__ u16 f2bf(float f) {
  u32 u = __builtin_bit_cast(u32, f);
  u32 r = (u + 0x7fffu + ((u >> 16) & 1u)) >> 16;
  return (u16)r;
}
__device__ __forceinline__ float bf2f(u16 h) {
  return __builtin_bit_cast(float, ((u32)h) << 16);
}
__device__ __forceinline__ void gload_lds16(const void* g, void* l) {
  __builtin_amdgcn_global_load_lds(
      (const __attribute__((address_space(1))) u32*)g,
      (__attribute__((address_space(3))) u32*)l, 16, 0, 0);
}

// ---------------- elementwise f32 -> bf16 ----------------
__global__ void __launch_bounds__(256) conv_f2b_vec(const float* __restrict__ in,
                                                    u16* __restrict__ out, const int n) {
  const int i = (blockIdx.x * 256 + threadIdx.x) * 4;
  if (i >= n) return;
  const float4 v = *(const float4*)(in + i);
  u16x4 o;
  o.x = f2bf(v.x); o.y = f2bf(v.y); o.z = f2bf(v.z); o.w = f2bf(v.w);
  *(u16x4*)(out + i) = o;
}

// ---------------- transpose fp32 [R][C] -> bf16 [C][R] ----------------
__global__ void __launch_bounds__(256) trans_f2b(const float* __restrict__ in,
                                                 u16* __restrict__ out, const int R, const int C) {
  __shared__ float tile[32][33];
  const int c0 = blockIdx.x * 32, r0 = blockIdx.y * 32;
  const int tx = threadIdx.x & 31, ty = threadIdx.x >> 5;
#pragma unroll
  for (int i = 0; i < 4; ++i)
    tile[ty + i * 8][tx] = in[(size_t)(r0 + ty + i * 8) * C + c0 + tx];
  __syncthreads();
#pragma unroll
  for (int i = 0; i < 4; ++i)
    out[(size_t)(c0 + ty + i * 8) * R + r0 + tx] = f2bf(tile[tx][ty + i * 8]);
}

// ---------------- transpose bf16 [R][C] -> bf16 [C][R] ----------------
__global__ void __launch_bounds__(256) trans_b2b(const u16* __restrict__ in,
                                                 u16* __restrict__ out, const int R, const int C) {
  __shared__ u16 tile[32][34];
  const int c0 = blockIdx.x * 32, r0 = blockIdx.y * 32;
  const int tx = threadIdx.x & 31, ty = threadIdx.x >> 5;
#pragma unroll
  for (int i = 0; i < 4; ++i)
    tile[ty + i * 8][tx] = in[(size_t)(r0 + ty + i * 8) * C + c0 + tx];
  __syncthreads();
#pragma unroll
  for (int i = 0; i < 4; ++i)
    out[(size_t)(c0 + ty + i * 8) * R + r0 + tx] = tile[tx][ty + i * 8];
}

// ---------------- RoPE in place on bf16 [SEQ][nheads*128] ----------------
__global__ void __launch_bounds__(256) rope_ip(u16* __restrict__ x, const int* __restrict__ pos,
                                               const int lognh) {
  const int idx = blockIdx.x * 256 + threadIdx.x;
  const int j = idx & 63;
  const int hh = (idx >> 6) & ((1 << lognh) - 1);
  const int s = idx >> (6 + lognh);
  if (s >= SEQ) return;
  const float p = (float)pos[s];
  const float invf = __expf((float)j * -0.14391156831212787f); // -ln(10000)/64
  const float ang = p * invf;
  const float c = cosf(ang), sn = sinf(ang);
  u16* bp = x + ((size_t)s << (7 + lognh)) + hh * 128 + j;
  const float x1 = bf2f(bp[0]), x2 = bf2f(bp[64]);
  bp[0] = f2bf(x1 * c - x2 * sn);
  bp[64] = f2bf(x2 * c + x1 * sn);
}

// ---------------- bf16 GEMM: C[M][N] = A[M][K] * B^T  (B stored [N][K]) ----------------
// 128x128 tile, BK=64, 4 waves (2x2), 16x16x32 MFMA, global_load_lds + XOR swizzle.
// Optional split: blocks with blockIdx.x >= nsplit use B2/C2 (for fused K/V projection).
__global__ void __launch_bounds__(256) gemm_bt(
    const u16* __restrict__ A, const u16* __restrict__ B, const u16* __restrict__ B2,
    void* __restrict__ Cp, void* __restrict__ Cp2,
    const int M, const int N, const int K, const int write_f32, const int nsplit) {
  __shared__ u16 As[128 * 64];
  __shared__ u16 Bs[128 * 64];
  const int t = threadIdx.x;
  const int lane = t & 63;
  const int w = t >> 6;
  const int wr = w >> 1, wc = w & 1;

  int bx = blockIdx.x;
  const u16* Bp = B;
  void* Cw = Cp;
  if (bx >= nsplit) { Bp = B2; Cw = Cp2; bx -= nsplit; }
  const int row0 = blockIdx.y * 128, col0 = bx * 128;

  f32x4 acc[4][4];
#pragma unroll
  for (int m = 0; m < 4; ++m)
#pragma unroll
    for (int n = 0; n < 4; ++n) acc[m][n] = f32x4{0.f, 0.f, 0.f, 0.f};

  const int nkt = K >> 6;
  for (int kt = 0; kt < nkt; ++kt) {
    const int k0 = kt << 6;
#pragma unroll
    for (int i = 0; i < 4; ++i) {
      const int o = (i * 256 + t) * 16;
      const int row = o >> 7;
      const int slot = (o >> 4) & 7;
      gload_lds16(A + (size_t)(row0 + row) * K + k0 + ((slot ^ (row & 7)) << 3), (char*)As + o);
    }
#pragma unroll
    for (int i = 0; i < 4; ++i) {
      const int o = (i * 256 + t) * 16;
      const int row = o >> 7;
      const int slot = (o >> 4) & 7;
      gload_lds16(Bp + (size_t)(col0 + row) * K + k0 + ((slot ^ (row & 7)) << 3), (char*)Bs + o);
    }
    __syncthreads();
#pragma unroll
    for (int kb = 0; kb < 2; ++kb) {
      bf16x8 af[4], bfr[4];
#pragma unroll
      for (int m = 0; m < 4; ++m) {
        const int row = wr * 64 + m * 16 + (lane & 15);
        const int slot = kb * 4 + (lane >> 4);
        af[m] = *(const bf16x8*)((const char*)As + row * 128 + ((slot ^ (row & 7)) << 4));
      }
#pragma unroll
      for (int n = 0; n < 4; ++n) {
        const int row = wc * 64 + n * 16 + (lane & 15);
        const int slot = kb * 4 + (lane >> 4);
        bfr[n] = *(const bf16x8*)((const char*)Bs + row * 128 + ((slot ^ (row & 7)) << 4));
      }
#pragma unroll
      for (int m = 0; m < 4; ++m)
#pragma unroll
        for (int n = 0; n < 4; ++n)
          acc[m][n] = __builtin_amdgcn_mfma_f32_16x16x32_bf16(af[m], bfr[n], acc[m][n], 0, 0, 0);
    }
    __syncthreads();
  }

  const int rb = row0 + wr * 64 + (lane >> 4) * 4;
  const int cbase = col0 + wc * 64 + (lane & 15);
  if (write_f32) {
    float* C = (float*)Cw;
#pragma unroll
    for (int m = 0; m < 4; ++m)
#pragma unroll
      for (int n = 0; n < 4; ++n)
#pragma unroll
        for (int r = 0; r < 4; ++r)
          C[(size_t)(rb + m * 16 + r) * N + cbase + n * 16] = acc[m][n][r];
  } else {
    u16* C = (u16*)Cw;
#pragma unroll
    for (int m = 0; m < 4; ++m)
#pragma unroll
      for (int n = 0; n < 4; ++n)
#pragma unroll
        for (int r = 0; r < 4; ++r)
          C[(size_t)(rb + m * 16 + r) * N + cbase + n * 16] = f2bf(acc[m][n][r]);
  }
}

// ---------------- causal GQA flash attention ----------------
// grid (32 heads, 32 q-blocks of 64). 4 waves x 16 q-rows. KVBLK=64.
// q: bf16 [SEQ][4096], k: bf16 [SEQ][1024], vt: bf16 [1024][SEQ], ctx out bf16 [SEQ][4096].
__global__ void __launch_bounds__(256) attn_fwd(const u16* __restrict__ q, const u16* __restrict__ k,
                                                const u16* __restrict__ vt, u16* __restrict__ ctx) {
  __shared__ u16 Ks[64 * 128];   // [sk][d], 256B rows, swizzled
  __shared__ u16 Vs[128 * 64];   // [d][sk], 128B rows, swizzled
  __shared__ u16 Ps[4][1024];    // per-wave P [16][64], 128B rows, swizzled
  const int t = threadIdx.x, lane = t & 63, w = t >> 6;
  const int h = blockIdx.x;
  const int qb = (int)gridDim.y - 1 - (int)blockIdx.y;  // long blocks first
  const int kvh = h >> 2;
  const int q0 = qb * 64;
  const int sq_base = q0 + w * 16;
  const int l15 = lane & 15, l4 = lane >> 4;

  bf16x8 qf[4];
  {
    const u16* qp = q + (size_t)(sq_base + l15) * (NHEADS * HD) + h * HD + l4 * 8;
#pragma unroll
    for (int kb = 0; kb < 4; ++kb) qf[kb] = *(const bf16x8*)(qp + kb * 32);
  }
  f32x4 po[8];
#pragma unroll
  for (int i = 0; i < 8; ++i) po[i] = f32x4{0.f, 0.f, 0.f, 0.f};
  float mrow[4] = {-1e30f, -1e30f, -1e30f, -1e30f};
  float lrow[4] = {0.f, 0.f, 0.f, 0.f};

  const int nb = qb + 1;
  for (int b = 0; b < nb; ++b) {
    const int kv0 = b * 64;
#pragma unroll
    for (int i = 0; i < 4; ++i) {
      const int o = (i * 256 + t) * 16;
      const int row = o >> 8;
      const int slot = (o >> 4) & 15;
      gload_lds16(k + (size_t)(kv0 + row) * (NKVH * HD) + kvh * HD + ((slot ^ (row & 7)) << 3),
                  (char*)Ks + o);
    }
#pragma unroll
    for (int i = 0; i < 4; ++i) {
      const int o = (i * 256 + t) * 16;
      const int row = o >> 7;
      const int slot = (o >> 4) & 7;
      gload_lds16(vt + (size_t)(kvh * HD + row) * SEQ + kv0 + ((slot ^ (row & 7)) << 3),
                  (char*)Vs + o);
    }
    __syncthreads();

    f32x4 sc[4];
#pragma unroll
    for (int c = 0; c < 4; ++c) sc[c] = f32x4{0.f, 0.f, 0.f, 0.f};
#pragma unroll
    for (int c = 0; c < 4; ++c) {
      const int row = c * 16 + l15;
#pragma unroll
      for (int kb = 0; kb < 4; ++kb) {
        const int slot = kb * 4 + l4;
        bf16x8 bk = *(const bf16x8*)((const char*)Ks + row * 256 + ((slot ^ (row & 7)) << 4));
        sc[c] = __builtin_amdgcn_mfma_f32_16x16x32_bf16(qf[kb], bk, sc[c], 0, 0, 0);
      }
    }

    float pv[4][4];
    const float scale = 0.08838834764831845f;
#pragma unroll
    for (int c = 0; c < 4; ++c) {
      const int sk = kv0 + c * 16 + l15;
#pragma unroll
      for (int r = 0; r < 4; ++r) {
        const int sq = sq_base + l4 * 4 + r;
        pv[c][r] = (sk > sq) ? -1e30f : sc[c][r] * scale;
      }
    }
#pragma unroll
    for (int r = 0; r < 4; ++r) {
      float rmax = fmaxf(fmaxf(pv[0][r], pv[1][r]), fmaxf(pv[2][r], pv[3][r]));
#pragma unroll
      for (int msk = 1; msk < 16; msk <<= 1) rmax = fmaxf(rmax, __shfl_xor(rmax, msk, 64));
      const float mnew = fmaxf(mrow[r], rmax);
      const float alpha = __expf(mrow[r] - mnew);
      float rs = 0.f;
#pragma unroll
      for (int c = 0; c < 4; ++c) {
        const float e = __expf(pv[c][r] - mnew);
        pv[c][r] = e;
        rs += e;
      }
#pragma unroll
      for (int msk = 1; msk < 16; msk <<= 1) rs += __shfl_xor(rs, msk, 64);
      lrow[r] = lrow[r] * alpha + rs;
      mrow[r] = mnew;
#pragma unroll
      for (int db = 0; db < 8; ++db) po[db][r] *= alpha;
    }
    // write P tile (swizzled) for MFMA A-frag layout
#pragma unroll
    for (int c = 0; c < 4; ++c)
#pragma unroll
      for (int r = 0; r < 4; ++r) {
        const int row = l4 * 4 + r;
        const int col = c * 16 + l15;
        const int slot = col >> 3;
        *(u16*)((char*)&Ps[w][0] + row * 128 + ((slot ^ (row & 7)) << 4) + ((col & 7) << 1)) =
            f2bf(pv[c][r]);
      }
    asm volatile("s_waitcnt lgkmcnt(0)" ::: "memory");
#pragma unroll
    for (int kb2 = 0; kb2 < 2; ++kb2) {
      const int prow = l15;
      const int pslot = kb2 * 4 + l4;
      bf16x8 pa = *(const bf16x8*)((const char*)&Ps[w][0] + prow * 128 + ((pslot ^ (prow & 7)) << 4));
#pragma unroll
      for (int db = 0; db < 8; ++db) {
        const int vrow = db * 16 + l15;
        bf16x8 bv = *(const bf16x8*)((const char*)Vs + vrow * 128 + ((pslot ^ (vrow & 7)) << 4));
        po[db] = __builtin_amdgcn_mfma_f32_16x16x32_bf16(pa, bv, po[db], 0, 0, 0);
      }
    }
    __syncthreads();
  }
#pragma unroll
  for (int db = 0; db < 8; ++db)
#pragma unroll
    for (int r = 0; r < 4; ++r) {
      const int sq = sq_base + l4 * 4 + r;
      const int d = db * 16 + l15;
      ctx[(size_t)sq * (NHEADS * HD) + h * HD + d] = f2bf(po[db][r] / lrow[r]);
    }
}

extern "C" void kernel_launch(void* const* d_in, const int* in_sizes, int n_in,
                              void* d_out, int out_size, void* d_ws, size_t ws_size,
                              hipStream_t stream) {
  const float* hs = (const float*)d_in[0];
  const int* pos = (const int*)d_in[1];
  const float* Wq = (const float*)d_in[2];
  const float* Wk = (const float*)d_in[3];
  const float* Wv = (const float*)d_in[4];
  const float* Wo = (const float*)d_in[5];

  u16* ws = (u16*)d_ws;
  u16* Xb = ws;                                   // [2048][4096]
  u16* Wqt = Xb + (size_t)2048 * 4096;            // [4096][4096]
  u16* Wkt = Wqt + (size_t)4096 * 4096;           // [1024][4096]
  u16* Wvt = Wkt + (size_t)1024 * 4096;           // [1024][4096]
  u16* Wot = Wvt + (size_t)1024 * 4096;           // [4096][4096]
  u16* qb = Wot + (size_t)4096 * 4096;            // [2048][4096]
  u16* kb = qb + (size_t)2048 * 4096;             // [2048][1024]
  u16* vb = kb + (size_t)2048 * 1024;             // [2048][1024]
  u16* vtb = vb + (size_t)2048 * 1024;            // [1024][2048]
  u16* ctx = vtb + (size_t)1024 * 2048;           // [2048][4096]
  const size_t need = ((size_t)(ctx - ws) + (size_t)2048 * 4096) * 2;
  if (ws_size < need) return;

  conv_f2b_vec<<<8192, 256, 0, stream>>>(hs, Xb, 2048 * 4096);
  trans_f2b<<<dim3(128, 128), 256, 0, stream>>>(Wq, Wqt, 4096, 4096);
  trans_f2b<<<dim3(32, 128), 256, 0, stream>>>(Wk, Wkt, 4096, 1024);
  trans_f2b<<<dim3(32, 128), 256, 0, stream>>>(Wv, Wvt, 4096, 1024);
  trans_f2b<<<dim3(128, 128), 256, 0, stream>>>(Wo, Wot, 4096, 4096);

  // Q projection
  gemm_bt<<<dim3(32, 16), 256, 0, stream>>>(Xb, Wqt, nullptr, qb, nullptr,
                                            2048, 4096, 4096, 0, 32);
  // fused K and V projections
  gemm_bt<<<dim3(16, 16), 256, 0, stream>>>(Xb, Wkt, Wvt, kb, vb,
                                            2048, 1024, 4096, 0, 8);

  rope_ip<<<16384, 256, 0, stream>>>(qb, pos, 5);
  rope_ip<<<4096, 256, 0, stream>>>(kb, pos, 3);

  trans_b2b<<<dim3(32, 64), 256, 0, stream>>>(vb, vtb, 2048, 1024);

  attn_fwd<<<dim3(32, 32), 256, 0, stream>>>(qb, kb, vtb, ctx);

  // output projection -> fp32 d_out
  gemm_bt<<<dim3(32, 16), 256, 0, stream>>>(ctx, Wot, nullptr, d_out, nullptr,
                                            2048, 4096, 4096, 1, 32);
}

// Round 2
// 388.099 us; speedup vs baseline: 1.0817x; 1.0817x over previous
//
#include <hip/hip_runtime.h>
#include <hip/hip_bf16.h>
#include <math.h>

#define SEQ 2048
#define NHEADS 32
#define NKVH 8
#define HD 128
#define HIDDEN 4096

typedef unsigned short u16;
typedef unsigned int u32;
typedef __attribute__((ext_vector_type(8))) __bf16 bf16x8;
typedef __attribute__((ext_vector_type(4))) float f32x4;
typedef __attribute__((ext_vector_type(4))) u16 u16x4;
typedef __attribute__((ext_vector_type(4))) u32 u32x4;

__device__ __forceinline__ u16 f2bf(float f) {
  u32 u = __builtin_bit_cast(u32, f);
  u32 r = (u + 0x7fffu + ((u >> 16) & 1u)) >> 16;
  return (u16)r;
}
__device__ __forceinline__ float bf2f(u16 h) {
  return __builtin_bit_cast(float, ((u32)h) << 16);
}
__device__ __forceinline__ void gload_lds16(const void* g, void* l) {
  __builtin_amdgcn_global_load_lds(
      (const __attribute__((address_space(1))) u32*)g,
      (__attribute__((address_space(3))) u32*)l, 16, 0, 0);
}

// ---------------- elementwise f32 -> bf16 ----------------
__global__ void __launch_bounds__(256) conv_f2b_vec(const float* __restrict__ in,
                                                    u16* __restrict__ out, const int n) {
  const int i = (blockIdx.x * 256 + threadIdx.x) * 4;
  if (i >= n) return;
  const float4 v = *(const float4*)(in + i);
  u16x4 o;
  o.x = f2bf(v.x); o.y = f2bf(v.y); o.z = f2bf(v.z); o.w = f2bf(v.w);
  *(u16x4*)(out + i) = o;
}

// ---------------- transpose fp32 [R][C] -> bf16 [C][R] ----------------
__global__ void __launch_bounds__(256) trans_f2b(const float* __restrict__ in,
                                                 u16* __restrict__ out, const int R, const int C) {
  __shared__ float tile[32][33];
  const int c0 = blockIdx.x * 32, r0 = blockIdx.y * 32;
  const int tx = threadIdx.x & 31, ty = threadIdx.x >> 5;
#pragma unroll
  for (int i = 0; i < 4; ++i)
    tile[ty + i * 8][tx] = in[(size_t)(r0 + ty + i * 8) * C + c0 + tx];
  __syncthreads();
#pragma unroll
  for (int i = 0; i < 4; ++i)
    out[(size_t)(c0 + ty + i * 8) * R + r0 + tx] = f2bf(tile[tx][ty + i * 8]);
}

// ---------------- transpose bf16 [R][C] -> bf16 [C][R] ----------------
__global__ void __launch_bounds__(256) trans_b2b(const u16* __restrict__ in,
                                                 u16* __restrict__ out, const int R, const int C) {
  __shared__ u16 tile[32][34];
  const int c0 = blockIdx.x * 32, r0 = blockIdx.y * 32;
  const int tx = threadIdx.x & 31, ty = threadIdx.x >> 5;
#pragma unroll
  for (int i = 0; i < 4; ++i)
    tile[ty + i * 8][tx] = in[(size_t)(r0 + ty + i * 8) * C + c0 + tx];
  __syncthreads();
#pragma unroll
  for (int i = 0; i < 4; ++i)
    out[(size_t)(c0 + ty + i * 8) * R + r0 + tx] = tile[tx][ty + i * 8];
}

// ---------------- RoPE in place on bf16 [SEQ][nheads*128], with output scale ----------------
__global__ void __launch_bounds__(256) rope_ip(u16* __restrict__ x, const int* __restrict__ pos,
                                               const int lognh, const float oscale) {
  const int idx = blockIdx.x * 256 + threadIdx.x;
  const int j = idx & 63;
  const int hh = (idx >> 6) & ((1 << lognh) - 1);
  const int s = idx >> (6 + lognh);
  if (s >= SEQ) return;
  const float p = (float)pos[s];
  const float invf = __expf((float)j * -0.14391156831212787f); // -ln(10000)/64
  const float ang = p * invf;
  const float c = cosf(ang), sn = sinf(ang);
  u16* bp = x + ((size_t)s << (7 + lognh)) + hh * 128 + j;
  const float x1 = bf2f(bp[0]), x2 = bf2f(bp[64]);
  bp[0] = f2bf((x1 * c - x2 * sn) * oscale);
  bp[64] = f2bf((x2 * c + x1 * sn) * oscale);
}

// ---------------- bf16 GEMM: C[M][N] = A[M][K] * B^T (B stored [N][K]), 3-way split ----------------
// 128x128 tile, BK=64, 4 waves (2x2), 16x16x32 MFMA, global_load_lds + XOR swizzle.
__global__ void __launch_bounds__(256) gemm_bt(
    const u16* __restrict__ A, const u16* __restrict__ B0, const u16* __restrict__ B1,
    const u16* __restrict__ B2, void* __restrict__ C0, void* __restrict__ C1,
    void* __restrict__ C2, const int K, const int n0t, const int n1t,
    const int N0, const int N1, const int N2, const int write_f32) {
  __shared__ u16 As[128 * 64];
  __shared__ u16 Bs[128 * 64];
  const int t = threadIdx.x;
  const int lane = t & 63;
  const int w = t >> 6;
  const int wr = w >> 1, wc = w & 1;

  int bx = blockIdx.x;
  const u16* Bp;
  char* Cw;
  int Nn;
  if (bx < n0t) { Bp = B0; Cw = (char*)C0; Nn = N0; }
  else if (bx < n0t + n1t) { bx -= n0t; Bp = B1; Cw = (char*)C1; Nn = N1; }
  else { bx -= n0t + n1t; Bp = B2; Cw = (char*)C2; Nn = N2; }
  const int row0 = blockIdx.y * 128, col0 = bx * 128;

  f32x4 acc[4][4];
#pragma unroll
  for (int m = 0; m < 4; ++m)
#pragma unroll
    for (int n = 0; n < 4; ++n) acc[m][n] = f32x4{0.f, 0.f, 0.f, 0.f};

  const int nkt = K >> 6;
  for (int kt = 0; kt < nkt; ++kt) {
    const int k0 = kt << 6;
#pragma unroll
    for (int i = 0; i < 4; ++i) {
      const int o = (i * 256 + t) * 16;
      const int row = o >> 7;
      const int slot = (o >> 4) & 7;
      gload_lds16(A + (size_t)(row0 + row) * K + k0 + ((slot ^ (row & 7)) << 3), (char*)As + o);
    }
#pragma unroll
    for (int i = 0; i < 4; ++i) {
      const int o = (i * 256 + t) * 16;
      const int row = o >> 7;
      const int slot = (o >> 4) & 7;
      gload_lds16(Bp + (size_t)(col0 + row) * K + k0 + ((slot ^ (row & 7)) << 3), (char*)Bs + o);
    }
    __syncthreads();
#pragma unroll
    for (int kb = 0; kb < 2; ++kb) {
      bf16x8 af[4], bfr[4];
#pragma unroll
      for (int m = 0; m < 4; ++m) {
        const int row = wr * 64 + m * 16 + (lane & 15);
        const int slot = kb * 4 + (lane >> 4);
        af[m] = *(const bf16x8*)((const char*)As + row * 128 + ((slot ^ (row & 7)) << 4));
      }
#pragma unroll
      for (int n = 0; n < 4; ++n) {
        const int row = wc * 64 + n * 16 + (lane & 15);
        const int slot = kb * 4 + (lane >> 4);
        bfr[n] = *(const bf16x8*)((const char*)Bs + row * 128 + ((slot ^ (row & 7)) << 4));
      }
#pragma unroll
      for (int m = 0; m < 4; ++m)
#pragma unroll
        for (int n = 0; n < 4; ++n)
          acc[m][n] = __builtin_amdgcn_mfma_f32_16x16x32_bf16(af[m], bfr[n], acc[m][n], 0, 0, 0);
    }
    __syncthreads();
  }

  const int rb = row0 + wr * 64 + (lane >> 4) * 4;
  const int cbase = col0 + wc * 64 + (lane & 15);
  if (write_f32) {
    float* C = (float*)Cw;
#pragma unroll
    for (int m = 0; m < 4; ++m)
#pragma unroll
      for (int n = 0; n < 4; ++n)
#pragma unroll
        for (int r = 0; r < 4; ++r)
          C[(size_t)(rb + m * 16 + r) * Nn + cbase + n * 16] = acc[m][n][r];
  } else {
    u16* C = (u16*)Cw;
#pragma unroll
    for (int m = 0; m < 4; ++m)
#pragma unroll
      for (int n = 0; n < 4; ++n)
#pragma unroll
        for (int r = 0; r < 4; ++r)
          C[(size_t)(rb + m * 16 + r) * Nn + cbase + n * 16] = f2bf(acc[m][n][r]);
  }
}

// ---------------- attention staging: K tile [64][128] + V^T tile [128][64], swizzled ----------------
__device__ __forceinline__ void stage_kv(const u16* __restrict__ k, const u16* __restrict__ vt,
                                         const int kvh, const int kv0, u16* KsB, u16* VsB,
                                         const int t) {
#pragma unroll
  for (int i = 0; i < 4; ++i) {
    const int o = (i * 256 + t) * 16;
    const int row = o >> 8;
    const int slot = (o >> 4) & 15;
    gload_lds16(k + (size_t)(kv0 + row) * (NKVH * HD) + kvh * HD + ((slot ^ (row & 7)) << 3),
                (char*)KsB + o);
  }
#pragma unroll
  for (int i = 0; i < 4; ++i) {
    const int o = (i * 256 + t) * 16;
    const int row = o >> 7;
    const int slot = (o >> 4) & 7;
    gload_lds16(vt + (size_t)(kvh * HD + row) * SEQ + kv0 + ((slot ^ (row & 7)) << 3),
                (char*)VsB + o);
  }
}

// ---------------- causal GQA flash attention, swapped-QK in-register softmax ----------------
// grid (32 heads, 32 q-blocks of 64). 4 waves x 16 q-rows. KVBLK=64, double-buffered LDS.
// q: bf16 [SEQ][4096] PRE-SCALED by 1/sqrt(D)*log2(e); k: bf16 [SEQ][1024]; vt: bf16 [1024][SEQ].
__global__ void __launch_bounds__(256) attn_fwd(const u16* __restrict__ q, const u16* __restrict__ k,
                                                const u16* __restrict__ vt, u16* __restrict__ ctx) {
  __shared__ u16 Ks[2][64 * 128];
  __shared__ u16 Vs[2][128 * 64];
  const int t = threadIdx.x, lane = t & 63, w = t >> 6;
  const int h = blockIdx.x;
  const int qb = (int)gridDim.y - 1 - (int)blockIdx.y;  // long blocks first
  const int kvh = h >> 2;
  const int q0 = qb * 64;
  const int sq_base = q0 + w * 16;
  const int l15 = lane & 15, l4 = lane >> 4;
  const int sq_abs = sq_base + l15;

  // Q fragment (B-operand): lane holds Q[sq_base + l15][kb*32 + l4*8 + j]
  bf16x8 qf[4];
  {
    const u16* qp = q + (size_t)sq_abs * (NHEADS * HD) + h * HD + l4 * 8;
#pragma unroll
    for (int kb = 0; kb < 4; ++kb) qf[kb] = *(const bf16x8*)(qp + kb * 32);
  }
  f32x4 po[8];
#pragma unroll
  for (int i = 0; i < 8; ++i) po[i] = f32x4{0.f, 0.f, 0.f, 0.f};
  float mrow = -1e30f;  // running max (log2 domain) for q = sq_abs
  float lrow = 0.f;     // running denom for q = sq_abs

  const int nb = qb + 1;
  stage_kv(k, vt, kvh, 0, Ks[0], Vs[0], t);
  __syncthreads();
  int cur = 0;

  for (int b = 0; b < nb; ++b) {
    if (b + 1 < nb) stage_kv(k, vt, kvh, (b + 1) * 64, Ks[cur ^ 1], Vs[cur ^ 1], t);

    // S^T = K * Q^T: lane holds S^T[kv = b*64 + c*16 + l4*4 + r][q = sq_abs]
    f32x4 st[4];
#pragma unroll
    for (int c = 0; c < 4; ++c) st[c] = f32x4{0.f, 0.f, 0.f, 0.f};
#pragma unroll
    for (int c = 0; c < 4; ++c) {
      const int row = c * 16 + l15;
#pragma unroll
      for (int kb = 0; kb < 4; ++kb) {
        const int slot = kb * 4 + l4;
        bf16x8 bk = *(const bf16x8*)((const char*)Ks[cur] + row * 256 + ((slot ^ (row & 7)) << 4));
        st[c] = __builtin_amdgcn_mfma_f32_16x16x32_bf16(bk, qf[kb], st[c], 0, 0, 0);
      }
    }

    if (b == nb - 1) {  // diagonal block: causal mask
#pragma unroll
      for (int c = 0; c < 4; ++c)
#pragma unroll
        for (int r = 0; r < 4; ++r) {
          const int sk = b * 64 + c * 16 + l4 * 4 + r;
          if (sk > sq_abs) st[c][r] = -1e30f;
        }
    }

    // per-q (per-lane) online softmax, base-2 domain
    float rmax = -3e38f;
#pragma unroll
    for (int c = 0; c < 4; ++c)
      rmax = fmaxf(rmax, fmaxf(fmaxf(st[c][0], st[c][1]), fmaxf(st[c][2], st[c][3])));
    rmax = fmaxf(rmax, __shfl_xor(rmax, 16, 64));
    rmax = fmaxf(rmax, __shfl_xor(rmax, 32, 64));

    const bool skip = __all(rmax <= mrow + 8.f);  // defer-max (T13)
    const float mnew = skip ? mrow : fmaxf(mrow, rmax);

    float rs = 0.f;
#pragma unroll
    for (int c = 0; c < 4; ++c) {
      const float e0 = exp2f(st[c][0] - mnew), e1 = exp2f(st[c][1] - mnew);
      const float e2 = exp2f(st[c][2] - mnew), e3 = exp2f(st[c][3] - mnew);
      st[c][0] = e0; st[c][1] = e1; st[c][2] = e2; st[c][3] = e3;
      rs += (e0 + e1) + (e2 + e3);
    }
    rs += __shfl_xor(rs, 16, 64);
    rs += __shfl_xor(rs, 32, 64);

    if (!skip) {
      const float alpha = exp2f(mrow - mnew);
      mrow = mnew;
      lrow = lrow * alpha + rs;
      float av[4];
#pragma unroll
      for (int r = 0; r < 4; ++r) av[r] = __shfl(alpha, l4 * 4 + r, 16);
#pragma unroll
      for (int db = 0; db < 8; ++db)
#pragma unroll
        for (int r = 0; r < 4; ++r) po[db][r] *= av[r];
    } else {
      lrow += rs;
    }

    // pack P^T to bf16 pairs: pk[c][i] = P[q=l15][kv c*16 + l4*4 + {2i,2i+1}]
    u32 pk[4][2];
#pragma unroll
    for (int c = 0; c < 4; ++c) {
      pk[c][0] = (u32)f2bf(st[c][0]) | ((u32)f2bf(st[c][1]) << 16);
      pk[c][1] = (u32)f2bf(st[c][2]) | ((u32)f2bf(st[c][3]) << 16);
    }
    // redistribute to PV A-frag: lane needs P[q=l15][kv = kb2*32 + l4*8 + j]
    const int src01 = l15 + ((lane & 16) << 1);  // l15 + 32*(l4&1)
    const int src23 = src01 + 16;
    const bool lo = (lane & 32) == 0;  // (l4>>1)==0 -> c_src = kb2*2
#pragma unroll
    for (int kb2 = 0; kb2 < 2; ++kb2) {
      const int c0 = kb2 * 2, c1 = c0 + 1;
      const u32 a0 = (u32)__shfl((int)pk[c0][0], src01, 64);
      const u32 a1 = (u32)__shfl((int)pk[c0][1], src01, 64);
      const u32 a2 = (u32)__shfl((int)pk[c0][0], src23, 64);
      const u32 a3 = (u32)__shfl((int)pk[c0][1], src23, 64);
      const u32 b0 = (u32)__shfl((int)pk[c1][0], src01, 64);
      const u32 b1 = (u32)__shfl((int)pk[c1][1], src01, 64);
      const u32 b2 = (u32)__shfl((int)pk[c1][0], src23, 64);
      const u32 b3 = (u32)__shfl((int)pk[c1][1], src23, 64);
      u32x4 wq;
      wq.x = lo ? a0 : b0;
      wq.y = lo ? a1 : b1;
      wq.z = lo ? a2 : b2;
      wq.w = lo ? a3 : b3;
      const bf16x8 pa = __builtin_bit_cast(bf16x8, wq);
#pragma unroll
      for (int db = 0; db < 8; ++db) {
        const int vrow = db * 16 + l15;
        const int pslot = kb2 * 4 + l4;
        bf16x8 bv = *(const bf16x8*)((const char*)Vs[cur] + vrow * 128 + ((pslot ^ (vrow & 7)) << 4));
        po[db] = __builtin_amdgcn_mfma_f32_16x16x32_bf16(pa, bv, po[db], 0, 0, 0);
      }
    }
    __syncthreads();
    cur ^= 1;
  }

  // po[db][r] = O[q = sq_base + l4*4 + r][d = db*16 + l15]; lrow lives at lane l15 == q-rel
  float rl[4];
#pragma unroll
  for (int r = 0; r < 4; ++r) rl[r] = 1.f / __shfl(lrow, l4 * 4 + r, 16);
#pragma unroll
  for (int db = 0; db < 8; ++db)
#pragma unroll
    for (int r = 0; r < 4; ++r) {
      const int sq = sq_base + l4 * 4 + r;
      const int d = db * 16 + l15;
      ctx[(size_t)sq * (NHEADS * HD) + h * HD + d] = f2bf(po[db][r] * rl[r]);
    }
}

extern "C" void kernel_launch(void* const* d_in, const int* in_sizes, int n_in,
                              void* d_out, int out_size, void* d_ws, size_t ws_size,
                              hipStream_t stream) {
  const float* hs = (const float*)d_in[0];
  const int* pos = (const int*)d_in[1];
  const float* Wq = (const float*)d_in[2];
  const float* Wk = (const float*)d_in[3];
  const float* Wv = (const float*)d_in[4];
  const float* Wo = (const float*)d_in[5];

  u16* ws = (u16*)d_ws;
  u16* Xb = ws;                                   // [2048][4096]
  u16* Wqt = Xb + (size_t)2048 * 4096;            // [4096][4096]
  u16* Wkt = Wqt + (size_t)4096 * 4096;           // [1024][4096]
  u16* Wvt = Wkt + (size_t)1024 * 4096;           // [1024][4096]
  u16* Wot = Wvt + (size_t)1024 * 4096;           // [4096][4096]
  u16* qb = Wot + (size_t)4096 * 4096;            // [2048][4096]
  u16* kb = qb + (size_t)2048 * 4096;             // [2048][1024]
  u16* vb = kb + (size_t)2048 * 1024;             // [2048][1024]
  u16* vtb = vb + (size_t)2048 * 1024;            // [1024][2048]
  u16* ctx = vtb + (size_t)1024 * 2048;           // [2048][4096]
  const size_t need = ((size_t)(ctx - ws) + (size_t)2048 * 4096) * 2;
  if (ws_size < need) return;

  conv_f2b_vec<<<8192, 256, 0, stream>>>(hs, Xb, 2048 * 4096);
  trans_f2b<<<dim3(128, 128), 256, 0, stream>>>(Wq, Wqt, 4096, 4096);
  trans_f2b<<<dim3(32, 128), 256, 0, stream>>>(Wk, Wkt, 4096, 1024);
  trans_f2b<<<dim3(32, 128), 256, 0, stream>>>(Wv, Wvt, 4096, 1024);
  trans_f2b<<<dim3(128, 128), 256, 0, stream>>>(Wo, Wot, 4096, 4096);

  // fused Q+K+V projections (one dispatch, 768 blocks)
  gemm_bt<<<dim3(48, 16), 256, 0, stream>>>(Xb, Wqt, Wkt, Wvt, qb, kb, vb,
                                            4096, 32, 8, 4096, 1024, 1024, 0);

  const float qscale = 0.08838834764831845f * 1.44269504088896340f;  // 1/sqrt(128)*log2(e)
  rope_ip<<<16384, 256, 0, stream>>>(qb, pos, 5, qscale);
  rope_ip<<<4096, 256, 0, stream>>>(kb, pos, 3, 1.0f);

  trans_b2b<<<dim3(32, 64), 256, 0, stream>>>(vb, vtb, 2048, 1024);

  attn_fwd<<<dim3(32, 32), 256, 0, stream>>>(qb, kb, vtb, ctx);

  // output projection -> fp32 d_out
  gemm_bt<<<dim3(32, 16), 256, 0, stream>>>(ctx, Wot, Wot, Wot, d_out, d_out, d_out,
                                            4096, 32, 0, 4096, 4096, 4096, 1);
}

// Round 3
// 375.694 us; speedup vs baseline: 1.1174x; 1.0330x over previous
//
#include <hip/hip_runtime.h>
#include <hip/hip_bf16.h>
#include <math.h>

#define SEQ 2048
#define NHEADS 32
#define NKVH 8
#define HD 128
#define HIDDEN 4096

typedef unsigned short u16;
typedef unsigned int u32;
typedef __attribute__((ext_vector_type(8))) __bf16 bf16x8;
typedef __attribute__((ext_vector_type(4))) float f32x4;
typedef __attribute__((ext_vector_type(4))) u16 u16x4;
typedef __attribute__((ext_vector_type(4))) u32 u32x4;

__device__ __forceinline__ u16 f2bf(float f) {
  u32 u = __builtin_bit_cast(u32, f);
  u32 r = (u + 0x7fffu + ((u >> 16) & 1u)) >> 16;
  return (u16)r;
}
__device__ __forceinline__ float bf2f(u16 h) {
  return __builtin_bit_cast(float, ((u32)h) << 16);
}
__device__ __forceinline__ void gload_lds16(const void* g, void* l) {
  __builtin_amdgcn_global_load_lds(
      (const __attribute__((address_space(1))) u32*)g,
      (__attribute__((address_space(3))) u32*)l, 16, 0, 0);
}

// ---------------- elementwise f32 -> bf16 ----------------
__global__ void __launch_bounds__(256) conv_f2b_vec(const float* __restrict__ in,
                                                    u16* __restrict__ out, const int n) {
  const int i = (blockIdx.x * 256 + threadIdx.x) * 4;
  if (i >= n) return;
  const float4 v = *(const float4*)(in + i);
  u16x4 o;
  o.x = f2bf(v.x); o.y = f2bf(v.y); o.z = f2bf(v.z); o.w = f2bf(v.w);
  *(u16x4*)(out + i) = o;
}

// ---------------- transpose fp32 [R][C] -> bf16 [C][R] ----------------
__global__ void __launch_bounds__(256) trans_f2b(const float* __restrict__ in,
                                                 u16* __restrict__ out, const int R, const int C) {
  __shared__ float tile[32][33];
  const int c0 = blockIdx.x * 32, r0 = blockIdx.y * 32;
  const int tx = threadIdx.x & 31, ty = threadIdx.x >> 5;
#pragma unroll
  for (int i = 0; i < 4; ++i)
    tile[ty + i * 8][tx] = in[(size_t)(r0 + ty + i * 8) * C + c0 + tx];
  __syncthreads();
#pragma unroll
  for (int i = 0; i < 4; ++i)
    out[(size_t)(c0 + ty + i * 8) * R + r0 + tx] = f2bf(tile[tx][ty + i * 8]);
}

// ---------------- transpose bf16 [R][C] -> bf16 [C][R] ----------------
__global__ void __launch_bounds__(256) trans_b2b(const u16* __restrict__ in,
                                                 u16* __restrict__ out, const int R, const int C) {
  __shared__ u16 tile[32][34];
  const int c0 = blockIdx.x * 32, r0 = blockIdx.y * 32;
  const int tx = threadIdx.x & 31, ty = threadIdx.x >> 5;
#pragma unroll
  for (int i = 0; i < 4; ++i)
    tile[ty + i * 8][tx] = in[(size_t)(r0 + ty + i * 8) * C + c0 + tx];
  __syncthreads();
#pragma unroll
  for (int i = 0; i < 4; ++i)
    out[(size_t)(c0 + ty + i * 8) * R + r0 + tx] = tile[tx][ty + i * 8];
}

// ---------------- RoPE in place on bf16 [SEQ][nheads*128], with output scale ----------------
__global__ void __launch_bounds__(256) rope_ip(u16* __restrict__ x, const int* __restrict__ pos,
                                               const int lognh, const float oscale) {
  const int idx = blockIdx.x * 256 + threadIdx.x;
  const int j = idx & 63;
  const int hh = (idx >> 6) & ((1 << lognh) - 1);
  const int s = idx >> (6 + lognh);
  if (s >= SEQ) return;
  const float p = (float)pos[s];
  const float invf = __expf((float)j * -0.14391156831212787f); // -ln(10000)/64
  const float ang = p * invf;
  const float c = cosf(ang), sn = sinf(ang);
  u16* bp = x + ((size_t)s << (7 + lognh)) + hh * 128 + j;
  const float x1 = bf2f(bp[0]), x2 = bf2f(bp[64]);
  bp[0] = f2bf((x1 * c - x2 * sn) * oscale);
  bp[64] = f2bf((x2 * c + x1 * sn) * oscale);
}

// ---------------- 8-phase 256-col GEMM: C[M][N] = A[M][K] * B^T (B stored [N][K]) ----------------
// BM = MF*32 (256 or 128), BN = 256, BK = 64, 512 threads = 8 waves (2M x 4N).
// Wave tile: (BM/2) x 64. Quadrant order (mh,nh): (0,0),(0,1),(1,1),(1,0).
// LDS regions: A halves by mh (rows permuted [wr][mh-rows]), B halves by nh ([wc][nh-rows]).
// Each phase stages the region freed one phase earlier; counted vmcnt at phases 3/7.
template <int MF, int MH, int NH>
__device__ __forceinline__ void mfmaq(f32x4 (&acc)[MF][4], const bf16x8 (&af)[MF / 2][2],
                                      const bf16x8 (&bfv)[2][2]) {
#pragma unroll
  for (int f = 0; f < MF / 2; ++f)
#pragma unroll
    for (int e = 0; e < 2; ++e)
#pragma unroll
      for (int ks = 0; ks < 2; ++ks)
        acc[MH * (MF / 2) + f][NH * 2 + e] = __builtin_amdgcn_mfma_f32_16x16x32_bf16(
            af[f][ks], bfv[e][ks], acc[MH * (MF / 2) + f][NH * 2 + e], 0, 0, 0);
}

template <int MF>
__global__ void __launch_bounds__(512, 2) gemm8p(
    const u16* __restrict__ A, const u16* __restrict__ B0q, const u16* __restrict__ B1q,
    const u16* __restrict__ B2q, void* __restrict__ C0, void* __restrict__ C1,
    void* __restrict__ C2, const int K, const int n0t, const int n1t,
    const int N0, const int N1, const int N2, const int write_f32) {
  constexpr int BM = MF * 32;
  constexpr int AHR = BM / 2;                 // rows per A half-region
  constexpr int GA = (AHR * 128) / 8192;      // gloads/thread per A half (2 or 1)
  __shared__ u16 As[2][2][AHR * 64];
  __shared__ u16 Bs[2][2][128 * 64];

  const int t = threadIdx.x;
  const int lane = t & 63;
  const int w = t >> 6;
  const int wr = w >> 2;   // 0..1
  const int wc = w & 3;    // 0..3
  const int l15 = lane & 15, l4 = lane >> 4;

  // XCD-aware swizzle (nwg divisible by 8 for both launches)
  const int nxt = gridDim.x;
  int flat = blockIdx.y * nxt + blockIdx.x;
  flat = (flat & 7) * ((nxt * (int)gridDim.y) >> 3) + (flat >> 3);
  int bxt = flat % nxt;
  const int byt = flat / nxt;

  const u16* Bp; char* Cw; int Nn;
  if (bxt < n0t) { Bp = B0q; Cw = (char*)C0; Nn = N0; }
  else if (bxt < n0t + n1t) { bxt -= n0t; Bp = B1q; Cw = (char*)C1; Nn = N1; }
  else { bxt -= n0t + n1t; Bp = B2q; Cw = (char*)C2; Nn = N2; }
  const int row0 = byt * BM, col0 = bxt * 256;

  auto stageA = [&](int buf, int half, int tile) {
#pragma unroll
    for (int g = 0; g < GA; ++g) {
      const int o = (g * 512 + t) * 16;
      const int ridx = o >> 7;
      const int slot = (o >> 4) & 7;
      const int gr = (ridx / (MF * 8)) * AHR + half * (MF * 8) + (ridx % (MF * 8));
      gload_lds16(A + (size_t)(row0 + gr) * K + (tile << 6) + ((slot ^ (ridx & 7)) << 3),
                  (char*)&As[buf][half][0] + o);
    }
  };
  auto stageB = [&](int buf, int half, int tile) {
#pragma unroll
    for (int g = 0; g < 2; ++g) {
      const int o = (g * 512 + t) * 16;
      const int ridx = o >> 7;
      const int slot = (o >> 4) & 7;
      const int gn = (ridx >> 5) * 64 + half * 32 + (ridx & 31);
      gload_lds16(Bp + (size_t)(col0 + gn) * K + (tile << 6) + ((slot ^ (ridx & 7)) << 3),
                  (char*)&Bs[buf][half][0] + o);
    }
  };

  bf16x8 af[MF / 2][2], bfv[2][2];
  auto loadA = [&](int buf, int half) {
#pragma unroll
    for (int f = 0; f < MF / 2; ++f)
#pragma unroll
      for (int ks = 0; ks < 2; ++ks) {
        const int idx = wr * (MF * 8) + f * 16 + l15;
        af[f][ks] = *(const bf16x8*)((const char*)&As[buf][half][0] + idx * 128 +
                                     (((ks * 4 + l4) ^ (idx & 7)) << 4));
      }
  };
  auto loadB = [&](int buf, int half) {
#pragma unroll
    for (int e = 0; e < 2; ++e)
#pragma unroll
      for (int ks = 0; ks < 2; ++ks) {
        const int idx = wc * 32 + e * 16 + l15;
        bfv[e][ks] = *(const bf16x8*)((const char*)&Bs[buf][half][0] + idx * 128 +
                                      (((ks * 4 + l4) ^ (idx & 7)) << 4));
      }
  };

  f32x4 acc[MF][4];
#pragma unroll
  for (int m_ = 0; m_ < MF; ++m_)
#pragma unroll
    for (int n_ = 0; n_ < 4; ++n_) acc[m_][n_] = f32x4{0.f, 0.f, 0.f, 0.f};

  const int nkt = K >> 6, nit = nkt >> 1;

#define VMW_STEADY                                                  \
  if constexpr (MF == 8) asm volatile("s_waitcnt vmcnt(4)" ::: "memory"); \
  else asm volatile("s_waitcnt vmcnt(3)" ::: "memory");
#define BAR __builtin_amdgcn_s_barrier()
#define PRIO1 __builtin_amdgcn_s_setprio(1)
#define PRIO0 __builtin_amdgcn_s_setprio(0)

  // prologue: full tile0 into buf0 + tile1's A0,B1 into buf1
  stageA(0, 0, 0); stageA(0, 1, 0); stageB(0, 0, 0); stageB(0, 1, 0);
  stageA(1, 0, 1); stageB(1, 1, 1);
  VMW_STEADY;
  BAR;

  for (int i = 0; i < nit; ++i) {
    const int tb = 2 * i;
    const bool g2 = (i + 1 < nit);
    // p0: Q(0,0) of buf0; stage buf1.A1 <- tile tb+1
    loadA(0, 0); loadB(0, 0);
    stageA(1, 1, tb + 1);
    BAR; PRIO1; mfmaq<MF, 0, 0>(acc, af, bfv); PRIO0; BAR;
    // p1: Q(0,1); stage buf1.B0 <- tb+1
    loadB(0, 1);
    stageB(1, 0, tb + 1);
    BAR; PRIO1; mfmaq<MF, 0, 1>(acc, af, bfv); PRIO0; BAR;
    // p2: Q(1,1); stage buf0.A0 <- tb+2
    loadA(0, 1);
    if (g2) stageA(0, 0, tb + 2);
    BAR; PRIO1; mfmaq<MF, 1, 1>(acc, af, bfv); PRIO0; BAR;
    // p3: Q(1,0); stage buf0.B1 <- tb+2 ; counted vmcnt
    loadB(0, 0);
    if (g2) stageB(0, 1, tb + 2);
    BAR; PRIO1; mfmaq<MF, 1, 0>(acc, af, bfv); PRIO0;
    if (g2) { VMW_STEADY; } else { asm volatile("s_waitcnt vmcnt(0)" ::: "memory"); }
    BAR;
    // p4: Q(0,0) of buf1; stage buf0.A1 <- tb+2
    loadA(1, 0); loadB(1, 0);
    if (g2) stageA(0, 1, tb + 2);
    BAR; PRIO1; mfmaq<MF, 0, 0>(acc, af, bfv); PRIO0; BAR;
    // p5: Q(0,1); stage buf0.B0 <- tb+2
    loadB(1, 1);
    if (g2) stageB(0, 0, tb + 2);
    BAR; PRIO1; mfmaq<MF, 0, 1>(acc, af, bfv); PRIO0; BAR;
    // p6: Q(1,1); stage buf1.A0 <- tb+3
    loadA(1, 1);
    if (g2) stageA(1, 0, tb + 3);
    BAR; PRIO1; mfmaq<MF, 1, 1>(acc, af, bfv); PRIO0; BAR;
    // p7: Q(1,0); stage buf1.B1 <- tb+3 ; counted vmcnt
    loadB(1, 0);
    if (g2) stageB(1, 1, tb + 3);
    BAR; PRIO1; mfmaq<MF, 1, 0>(acc, af, bfv); PRIO0;
    if (g2) { VMW_STEADY; } else { asm volatile("s_waitcnt vmcnt(0)" ::: "memory"); }
    BAR;
  }
#undef VMW_STEADY
#undef BAR
#undef PRIO1
#undef PRIO0

  // epilogue
  if (write_f32) {
    float* C = (float*)Cw;
#pragma unroll
    for (int am = 0; am < MF; ++am) {
      const int row = row0 + wr * AHR + (am / (MF / 2)) * (MF * 8) + (am % (MF / 2)) * 16 + l4 * 4;
#pragma unroll
      for (int an = 0; an < 4; ++an) {
        const int col = col0 + wc * 64 + (an >> 1) * 32 + (an & 1) * 16 + l15;
#pragma unroll
        for (int r = 0; r < 4; ++r)
          C[(size_t)(row + r) * Nn + col] = acc[am][an][r];
      }
    }
  } else {
    u16* C = (u16*)Cw;
#pragma unroll
    for (int am = 0; am < MF; ++am) {
      const int row = row0 + wr * AHR + (am / (MF / 2)) * (MF * 8) + (am % (MF / 2)) * 16 + l4 * 4;
#pragma unroll
      for (int an = 0; an < 4; ++an) {
        const int col = col0 + wc * 64 + (an >> 1) * 32 + (an & 1) * 16 + l15;
#pragma unroll
        for (int r = 0; r < 4; ++r)
          C[(size_t)(row + r) * Nn + col] = f2bf(acc[am][an][r]);
      }
    }
  }
}

// ---------------- attention staging: K tile [64][128] + V^T tile [128][64], swizzled ----------------
__device__ __forceinline__ void stage_kv(const u16* __restrict__ k, const u16* __restrict__ vt,
                                         const int kvh, const int kv0, u16* KsB, u16* VsB,
                                         const int t) {
#pragma unroll
  for (int i = 0; i < 4; ++i) {
    const int o = (i * 256 + t) * 16;
    const int row = o >> 8;
    const int slot = (o >> 4) & 15;
    gload_lds16(k + (size_t)(kv0 + row) * (NKVH * HD) + kvh * HD + ((slot ^ (row & 7)) << 3),
                (char*)KsB + o);
  }
#pragma unroll
  for (int i = 0; i < 4; ++i) {
    const int o = (i * 256 + t) * 16;
    const int row = o >> 7;
    const int slot = (o >> 4) & 7;
    gload_lds16(vt + (size_t)(kvh * HD + row) * SEQ + kv0 + ((slot ^ (row & 7)) << 3),
                (char*)VsB + o);
  }
}

// ---------------- causal GQA flash attention, swapped-QK in-register softmax ----------------
__global__ void __launch_bounds__(256) attn_fwd(const u16* __restrict__ q, const u16* __restrict__ k,
                                                const u16* __restrict__ vt, u16* __restrict__ ctx) {
  __shared__ u16 Ks[2][64 * 128];
  __shared__ u16 Vs[2][128 * 64];
  const int t = threadIdx.x, lane = t & 63, w = t >> 6;
  const int h = blockIdx.x;
  const int qb = (int)gridDim.y - 1 - (int)blockIdx.y;  // long blocks first
  const int kvh = h >> 2;
  const int q0 = qb * 64;
  const int sq_base = q0 + w * 16;
  const int l15 = lane & 15, l4 = lane >> 4;
  const int sq_abs = sq_base + l15;

  bf16x8 qf[4];
  {
    const u16* qp = q + (size_t)sq_abs * (NHEADS * HD) + h * HD + l4 * 8;
#pragma unroll
    for (int kb = 0; kb < 4; ++kb) qf[kb] = *(const bf16x8*)(qp + kb * 32);
  }
  f32x4 po[8];
#pragma unroll
  for (int i = 0; i < 8; ++i) po[i] = f32x4{0.f, 0.f, 0.f, 0.f};
  float mrow = -1e30f;
  float lrow = 0.f;

  const int nb = qb + 1;
  stage_kv(k, vt, kvh, 0, Ks[0], Vs[0], t);
  __syncthreads();
  int cur = 0;

  for (int b = 0; b < nb; ++b) {
    if (b + 1 < nb) stage_kv(k, vt, kvh, (b + 1) * 64, Ks[cur ^ 1], Vs[cur ^ 1], t);

    f32x4 st[4];
#pragma unroll
    for (int c = 0; c < 4; ++c) st[c] = f32x4{0.f, 0.f, 0.f, 0.f};
#pragma unroll
    for (int c = 0; c < 4; ++c) {
      const int row = c * 16 + l15;
#pragma unroll
      for (int kb = 0; kb < 4; ++kb) {
        const int slot = kb * 4 + l4;
        bf16x8 bk = *(const bf16x8*)((const char*)Ks[cur] + row * 256 + ((slot ^ (row & 7)) << 4));
        st[c] = __builtin_amdgcn_mfma_f32_16x16x32_bf16(bk, qf[kb], st[c], 0, 0, 0);
      }
    }

    if (b == nb - 1) {
#pragma unroll
      for (int c = 0; c < 4; ++c)
#pragma unroll
        for (int r = 0; r < 4; ++r) {
          const int sk = b * 64 + c * 16 + l4 * 4 + r;
          if (sk > sq_abs) st[c][r] = -1e30f;
        }
    }

    float rmax = -3e38f;
#pragma unroll
    for (int c = 0; c < 4; ++c)
      rmax = fmaxf(rmax, fmaxf(fmaxf(st[c][0], st[c][1]), fmaxf(st[c][2], st[c][3])));
    rmax = fmaxf(rmax, __shfl_xor(rmax, 16, 64));
    rmax = fmaxf(rmax, __shfl_xor(rmax, 32, 64));

    const bool skip = __all(rmax <= mrow + 8.f);
    const float mnew = skip ? mrow : fmaxf(mrow, rmax);

    float rs = 0.f;
#pragma unroll
    for (int c = 0; c < 4; ++c) {
      const float e0 = exp2f(st[c][0] - mnew), e1 = exp2f(st[c][1] - mnew);
      const float e2 = exp2f(st[c][2] - mnew), e3 = exp2f(st[c][3] - mnew);
      st[c][0] = e0; st[c][1] = e1; st[c][2] = e2; st[c][3] = e3;
      rs += (e0 + e1) + (e2 + e3);
    }
    rs += __shfl_xor(rs, 16, 64);
    rs += __shfl_xor(rs, 32, 64);

    if (!skip) {
      const float alpha = exp2f(mrow - mnew);
      mrow = mnew;
      lrow = lrow * alpha + rs;
      float av[4];
#pragma unroll
      for (int r = 0; r < 4; ++r) av[r] = __shfl(alpha, l4 * 4 + r, 16);
#pragma unroll
      for (int db = 0; db < 8; ++db)
#pragma unroll
        for (int r = 0; r < 4; ++r) po[db][r] *= av[r];
    } else {
      lrow += rs;
    }

    u32 pk[4][2];
#pragma unroll
    for (int c = 0; c < 4; ++c) {
      pk[c][0] = (u32)f2bf(st[c][0]) | ((u32)f2bf(st[c][1]) << 16);
      pk[c][1] = (u32)f2bf(st[c][2]) | ((u32)f2bf(st[c][3]) << 16);
    }
    const int src01 = l15 + ((lane & 16) << 1);
    const int src23 = src01 + 16;
    const bool lo = (lane & 32) == 0;
#pragma unroll
    for (int kb2 = 0; kb2 < 2; ++kb2) {
      const int c0 = kb2 * 2, c1 = c0 + 1;
      const u32 a0 = (u32)__shfl((int)pk[c0][0], src01, 64);
      const u32 a1 = (u32)__shfl((int)pk[c0][1], src01, 64);
      const u32 a2 = (u32)__shfl((int)pk[c0][0], src23, 64);
      const u32 a3 = (u32)__shfl((int)pk[c0][1], src23, 64);
      const u32 b0 = (u32)__shfl((int)pk[c1][0], src01, 64);
      const u32 b1 = (u32)__shfl((int)pk[c1][1], src01, 64);
      const u32 b2 = (u32)__shfl((int)pk[c1][0], src23, 64);
      const u32 b3 = (u32)__shfl((int)pk[c1][1], src23, 64);
      u32x4 wq;
      wq.x = lo ? a0 : b0;
      wq.y = lo ? a1 : b1;
      wq.z = lo ? a2 : b2;
      wq.w = lo ? a3 : b3;
      const bf16x8 pa = __builtin_bit_cast(bf16x8, wq);
#pragma unroll
      for (int db = 0; db < 8; ++db) {
        const int vrow = db * 16 + l15;
        const int pslot = kb2 * 4 + l4;
        bf16x8 bv = *(const bf16x8*)((const char*)Vs[cur] + vrow * 128 + ((pslot ^ (vrow & 7)) << 4));
        po[db] = __builtin_amdgcn_mfma_f32_16x16x32_bf16(pa, bv, po[db], 0, 0, 0);
      }
    }
    __syncthreads();
    cur ^= 1;
  }

  float rl[4];
#pragma unroll
  for (int r = 0; r < 4; ++r) rl[r] = 1.f / __shfl(lrow, l4 * 4 + r, 16);
#pragma unroll
  for (int db = 0; db < 8; ++db)
#pragma unroll
    for (int r = 0; r < 4; ++r) {
      const int sq = sq_base + l4 * 4 + r;
      const int d = db * 16 + l15;
      ctx[(size_t)sq * (NHEADS * HD) + h * HD + d] = f2bf(po[db][r] * rl[r]);
    }
}

extern "C" void kernel_launch(void* const* d_in, const int* in_sizes, int n_in,
                              void* d_out, int out_size, void* d_ws, size_t ws_size,
                              hipStream_t stream) {
  const float* hs = (const float*)d_in[0];
  const int* pos = (const int*)d_in[1];
  const float* Wq = (const float*)d_in[2];
  const float* Wk = (const float*)d_in[3];
  const float* Wv = (const float*)d_in[4];
  const float* Wo = (const float*)d_in[5];

  u16* ws = (u16*)d_ws;
  u16* Xb = ws;                                   // [2048][4096]
  u16* Wqt = Xb + (size_t)2048 * 4096;            // [4096][4096]
  u16* Wkt = Wqt + (size_t)4096 * 4096;           // [1024][4096]
  u16* Wvt = Wkt + (size_t)1024 * 4096;           // [1024][4096]
  u16* Wot = Wvt + (size_t)1024 * 4096;           // [4096][4096]
  u16* qb = Wot + (size_t)4096 * 4096;            // [2048][4096]
  u16* kb = qb + (size_t)2048 * 4096;             // [2048][1024]
  u16* vb = kb + (size_t)2048 * 1024;             // [2048][1024]
  u16* vtb = vb + (size_t)2048 * 1024;            // [1024][2048]
  u16* ctx = vtb + (size_t)1024 * 2048;           // [2048][4096]
  const size_t need = ((size_t)(ctx - ws) + (size_t)2048 * 4096) * 2;
  if (ws_size < need) return;

  conv_f2b_vec<<<8192, 256, 0, stream>>>(hs, Xb, 2048 * 4096);
  trans_f2b<<<dim3(128, 128), 256, 0, stream>>>(Wq, Wqt, 4096, 4096);
  trans_f2b<<<dim3(32, 128), 256, 0, stream>>>(Wk, Wkt, 4096, 1024);
  trans_f2b<<<dim3(32, 128), 256, 0, stream>>>(Wv, Wvt, 4096, 1024);
  trans_f2b<<<dim3(128, 128), 256, 0, stream>>>(Wo, Wot, 4096, 4096);

  // fused Q+K+V projections: BM=256, grid 24x8=192 blocks
  gemm8p<8><<<dim3(24, 8), 512, 0, stream>>>(Xb, Wqt, Wkt, Wvt, qb, kb, vb,
                                             4096, 16, 4, 4096, 1024, 1024, 0);

  const float qscale = 0.08838834764831845f * 1.44269504088896340f;  // 1/sqrt(128)*log2(e)
  rope_ip<<<16384, 256, 0, stream>>>(qb, pos, 5, qscale);
  rope_ip<<<4096, 256, 0, stream>>>(kb, pos, 3, 1.0f);

  trans_b2b<<<dim3(32, 64), 256, 0, stream>>>(vb, vtb, 2048, 1024);

  attn_fwd<<<dim3(32, 32), 256, 0, stream>>>(qb, kb, vtb, ctx);

  // output projection -> fp32 d_out: BM=128, grid 16x16=256 blocks
  gemm8p<4><<<dim3(16, 16), 512, 0, stream>>>(ctx, Wot, Wot, Wot, d_out, d_out, d_out,
                                              4096, 16, 0, 4096, 4096, 4096, 1);
}

// Round 4
// 351.523 us; speedup vs baseline: 1.1942x; 1.0688x over previous
//
#include <hip/hip_runtime.h>
#include <hip/hip_bf16.h>
#include <math.h>

#define SEQ 2048
#define NHEADS 32
#define NKVH 8
#define HD 128
#define HIDDEN 4096

typedef unsigned short u16;
typedef unsigned int u32;
typedef __attribute__((ext_vector_type(8))) __bf16 bf16x8;
typedef __attribute__((ext_vector_type(4))) float f32x4;
typedef __attribute__((ext_vector_type(16))) float f32x16;
typedef __attribute__((ext_vector_type(4))) u16 u16x4;
typedef __attribute__((ext_vector_type(4))) u32 u32x4;

__device__ __forceinline__ u16 f2bf(float f) {
  u32 u = __builtin_bit_cast(u32, f);
  u32 r = (u + 0x7fffu + ((u >> 16) & 1u)) >> 16;
  return (u16)r;
}
__device__ __forceinline__ float bf2f(u16 h) {
  return __builtin_bit_cast(float, ((u32)h) << 16);
}
__device__ __forceinline__ void gload_lds16(const void* g, void* l) {
  __builtin_amdgcn_global_load_lds(
      (const __attribute__((address_space(1))) u32*)g,
      (__attribute__((address_space(3))) u32*)l, 16, 0, 0);
}

#define BAR __builtin_amdgcn_s_barrier()
#define PRIO1 __builtin_amdgcn_s_setprio(1)
#define PRIO0 __builtin_amdgcn_s_setprio(0)
#define VMW(n) asm volatile("s_waitcnt vmcnt(" #n ")" ::: "memory")

// ---------------- elementwise f32 -> bf16 ----------------
__global__ void __launch_bounds__(256) conv_f2b_vec(const float* __restrict__ in,
                                                    u16* __restrict__ out, const int n) {
  const int i = (blockIdx.x * 256 + threadIdx.x) * 4;
  if (i >= n) return;
  const float4 v = *(const float4*)(in + i);
  u16x4 o;
  o.x = f2bf(v.x); o.y = f2bf(v.y); o.z = f2bf(v.z); o.w = f2bf(v.w);
  *(u16x4*)(out + i) = o;
}

// ---------------- transpose fp32 [R][C] -> bf16 [C][R] ----------------
__global__ void __launch_bounds__(256) trans_f2b(const float* __restrict__ in,
                                                 u16* __restrict__ out, const int R, const int C) {
  __shared__ float tile[32][33];
  const int c0 = blockIdx.x * 32, r0 = blockIdx.y * 32;
  const int tx = threadIdx.x & 31, ty = threadIdx.x >> 5;
#pragma unroll
  for (int i = 0; i < 4; ++i)
    tile[ty + i * 8][tx] = in[(size_t)(r0 + ty + i * 8) * C + c0 + tx];
  __syncthreads();
#pragma unroll
  for (int i = 0; i < 4; ++i)
    out[(size_t)(c0 + ty + i * 8) * R + r0 + tx] = f2bf(tile[tx][ty + i * 8]);
}

// ---------------- transpose bf16 [R][C] -> bf16 [C][R] ----------------
__global__ void __launch_bounds__(256) trans_b2b(const u16* __restrict__ in,
                                                 u16* __restrict__ out, const int R, const int C) {
  __shared__ u16 tile[32][34];
  const int c0 = blockIdx.x * 32, r0 = blockIdx.y * 32;
  const int tx = threadIdx.x & 31, ty = threadIdx.x >> 5;
#pragma unroll
  for (int i = 0; i < 4; ++i)
    tile[ty + i * 8][tx] = in[(size_t)(r0 + ty + i * 8) * C + c0 + tx];
  __syncthreads();
#pragma unroll
  for (int i = 0; i < 4; ++i)
    out[(size_t)(c0 + ty + i * 8) * R + r0 + tx] = tile[tx][ty + i * 8];
}

// ---------------- RoPE in place on bf16 [SEQ][nheads*128], with output scale ----------------
__global__ void __launch_bounds__(256) rope_ip(u16* __restrict__ x, const int* __restrict__ pos,
                                               const int lognh, const float oscale) {
  const int idx = blockIdx.x * 256 + threadIdx.x;
  const int j = idx & 63;
  const int hh = (idx >> 6) & ((1 << lognh) - 1);
  const int s = idx >> (6 + lognh);
  if (s >= SEQ) return;
  const float p = (float)pos[s];
  const float invf = __expf((float)j * -0.14391156831212787f); // -ln(10000)/64
  const float ang = p * invf;
  const float c = cosf(ang), sn = sinf(ang);
  u16* bp = x + ((size_t)s << (7 + lognh)) + hh * 128 + j;
  const float x1 = bf2f(bp[0]), x2 = bf2f(bp[64]);
  bp[0] = f2bf((x1 * c - x2 * sn) * oscale);
  bp[64] = f2bf((x2 * c + x1 * sn) * oscale);
}

// ================= 8-phase GEMM, 32x32x16 MFMA, BM=BN=256, BK=64 =================
// QKV projections (3-way B split) + 64 spare blocks fold the Wo f32->bf16 transpose.
// 512 threads = 8 waves (2M x 4N); wave tile 128x64; quadrants (mh,nh): (0,0),(0,1),(1,1),(1,0).
template <int MH, int NH>
__device__ __forceinline__ void mfq32(f32x16 (&acc)[4][2], const bf16x8 (&afr)[2][4],
                                      const bf16x8 (&b)[4]) {
#pragma unroll
  for (int f = 0; f < 2; ++f)
#pragma unroll
    for (int ks = 0; ks < 4; ++ks)
      acc[MH * 2 + f][NH] = __builtin_amdgcn_mfma_f32_32x32x16_bf16(
          afr[f][ks], b[ks], acc[MH * 2 + f][NH], 0, 0, 0);
}

__global__ void __launch_bounds__(512, 2) gemm8p32(
    const u16* __restrict__ A, const u16* __restrict__ B0q, const u16* __restrict__ B1q,
    const u16* __restrict__ B2q, u16* __restrict__ C0, u16* __restrict__ C1,
    u16* __restrict__ C2, const float* __restrict__ Wsrc, u16* __restrict__ Wdst) {
  __shared__ u16 As[2][2][128 * 64];
  __shared__ u16 Bs[2][2][128 * 64];
  const int t = threadIdx.x;
  const int flat = blockIdx.x;
  const int swz = (flat & 7) * 32 + (flat >> 3);  // XCD swizzle over 256

  if (swz >= 192) {  // ---- folded Wo transpose on XCDs 6,7 ----
    const int wid = swz - 192;  // 0..63, rows [wid*64, +64)
    float* tf = (float*)&As[0][0][0];  // 64x65 f32 = 16.6 KB
    const int tx = t & 63, ty = t >> 6;
    const int r0 = wid * 64;
    for (int ct = 0; ct < 64; ++ct) {
      const int c0 = ct * 64;
#pragma unroll
      for (int i = 0; i < 8; ++i)
        tf[(ty + i * 8) * 65 + tx] = Wsrc[(size_t)(r0 + ty + i * 8) * 4096 + c0 + tx];
      __syncthreads();
#pragma unroll
      for (int i = 0; i < 8; ++i)
        Wdst[(size_t)(c0 + ty + i * 8) * 4096 + r0 + tx] = f2bf(tf[tx * 65 + ty + i * 8]);
      __syncthreads();
    }
    return;
  }

  const int lane = t & 63, w = t >> 6;
  const int wr = w >> 2, wc = w & 3;
  const int l31 = lane & 31, l5 = lane >> 5;

  int bxt = swz % 24;
  const int byt = swz / 24;
  const u16* Bp; u16* Cw; int Nn;
  if (bxt < 16) { Bp = B0q; Cw = C0; Nn = 4096; }
  else if (bxt < 20) { bxt -= 16; Bp = B1q; Cw = C1; Nn = 1024; }
  else { bxt -= 20; Bp = B2q; Cw = C2; Nn = 1024; }
  const int row0 = byt * 256, col0 = bxt * 256;

  auto stageA = [&](int buf, int half, int tile) {
#pragma unroll
    for (int g = 0; g < 2; ++g) {
      const int o = (g * 512 + t) * 16;
      const int ridx = o >> 7;
      const int slot = (o >> 4) & 7;
      const int gr = (ridx >> 6) * 128 + half * 64 + (ridx & 63);
      gload_lds16(A + (size_t)(row0 + gr) * 4096 + (tile << 6) + ((slot ^ (ridx & 7)) << 3),
                  (char*)&As[buf][half][0] + o);
    }
  };
  auto stageB = [&](int buf, int half, int tile) {
#pragma unroll
    for (int g = 0; g < 2; ++g) {
      const int o = (g * 512 + t) * 16;
      const int ridx = o >> 7;
      const int slot = (o >> 4) & 7;
      const int gn = (ridx >> 5) * 64 + half * 32 + (ridx & 31);
      gload_lds16(Bp + (size_t)(col0 + gn) * 4096 + (tile << 6) + ((slot ^ (ridx & 7)) << 3),
                  (char*)&Bs[buf][half][0] + o);
    }
  };

  bf16x8 afr[2][4], bf0[4], bf1[4];
  auto loadA32 = [&](int buf, int half) {
#pragma unroll
    for (int f = 0; f < 2; ++f)
#pragma unroll
      for (int ks = 0; ks < 4; ++ks) {
        const int idx = wr * 64 + f * 32 + l31;
        const int slot = ks * 2 + l5;
        afr[f][ks] = *(const bf16x8*)((const char*)&As[buf][half][0] + idx * 128 +
                                      ((slot ^ (idx & 7)) << 4));
      }
  };
  auto loadB32 = [&](int buf, int half, bf16x8 (&dst)[4]) {
#pragma unroll
    for (int ks = 0; ks < 4; ++ks) {
      const int idx = wc * 32 + l31;
      const int slot = ks * 2 + l5;
      dst[ks] = *(const bf16x8*)((const char*)&Bs[buf][half][0] + idx * 128 +
                                 ((slot ^ (idx & 7)) << 4));
    }
  };

  f32x16 acc[4][2];
#pragma unroll
  for (int m_ = 0; m_ < 4; ++m_)
#pragma unroll
    for (int n_ = 0; n_ < 2; ++n_)
#pragma unroll
      for (int e = 0; e < 16; ++e) acc[m_][n_][e] = 0.f;

  const int nit = (4096 >> 6) >> 1;  // 32

  // prologue: tile0 full into buf0; tile1 A0,B1 into buf1
  stageA(0, 0, 0); stageA(0, 1, 0); stageB(0, 0, 0); stageB(0, 1, 0);
  stageA(1, 0, 1); stageB(1, 1, 1);
  VMW(4);
  BAR;

  for (int i = 0; i < nit; ++i) {
    const int tb = 2 * i;
    const bool g2 = (i + 1 < nit);
    // p0
    loadA32(0, 0); loadB32(0, 0, bf0);
    stageA(1, 1, tb + 1);
    BAR; PRIO1; mfq32<0, 0>(acc, afr, bf0); PRIO0; BAR;
    // p1
    loadB32(0, 1, bf1);
    stageB(1, 0, tb + 1);
    BAR; PRIO1; mfq32<0, 1>(acc, afr, bf1); PRIO0; BAR;
    // p2
    loadA32(0, 1);
    if (g2) stageA(0, 0, tb + 2);
    BAR; PRIO1; mfq32<1, 1>(acc, afr, bf1); PRIO0; BAR;
    // p3 (B-half0 reused from registers)
    if (g2) stageB(0, 1, tb + 2);
    BAR; PRIO1; mfq32<1, 0>(acc, afr, bf0); PRIO0;
    if (g2) { VMW(4); } else { VMW(0); }
    BAR;
    // p4
    loadA32(1, 0); loadB32(1, 0, bf0);
    if (g2) stageA(0, 1, tb + 2);
    BAR; PRIO1; mfq32<0, 0>(acc, afr, bf0); PRIO0; BAR;
    // p5
    loadB32(1, 1, bf1);
    if (g2) stageB(0, 0, tb + 2);
    BAR; PRIO1; mfq32<0, 1>(acc, afr, bf1); PRIO0; BAR;
    // p6
    loadA32(1, 1);
    if (g2) stageA(1, 0, tb + 3);
    BAR; PRIO1; mfq32<1, 1>(acc, afr, bf1); PRIO0; BAR;
    // p7 (B-half0 reused)
    if (g2) stageB(1, 1, tb + 3);
    BAR; PRIO1; mfq32<1, 0>(acc, afr, bf0); PRIO0;
    if (g2) { VMW(4); } else { VMW(0); }
    BAR;
  }

  // epilogue: 32x32 D layout col=l&31, row=(reg&3)+8*(reg>>2)+4*(l>>5)
#pragma unroll
  for (int am = 0; am < 4; ++am)
#pragma unroll
    for (int an = 0; an < 2; ++an) {
      const int colb = col0 + wc * 64 + an * 32 + l31;
#pragma unroll
      for (int q = 0; q < 4; ++q) {
        const int rowb = row0 + wr * 128 + am * 32 + q * 8 + l5 * 4;
#pragma unroll
        for (int rr = 0; rr < 4; ++rr)
          Cw[(size_t)(rowb + rr) * Nn + colb] = f2bf(acc[am][an][q * 4 + rr]);
      }
    }
}

// ================= 8-phase GEMM, 16x16x32 MFMA, BM=128, BN=256 (Wo, f32 out) =================
template <int MH, int NH>
__device__ __forceinline__ void mfq16(f32x4 (&acc)[4][4], const bf16x8 (&af)[2][2],
                                      const bf16x8 (&b)[2][2]) {
#pragma unroll
  for (int f = 0; f < 2; ++f)
#pragma unroll
    for (int e = 0; e < 2; ++e)
#pragma unroll
      for (int ks = 0; ks < 2; ++ks)
        acc[MH * 2 + f][NH * 2 + e] = __builtin_amdgcn_mfma_f32_16x16x32_bf16(
            af[f][ks], b[e][ks], acc[MH * 2 + f][NH * 2 + e], 0, 0, 0);
}

__global__ void __launch_bounds__(512, 2) gemm8p16(
    const u16* __restrict__ A, const u16* __restrict__ B, float* __restrict__ C) {
  __shared__ u16 As[2][2][64 * 64];
  __shared__ u16 Bs[2][2][128 * 64];
  const int t = threadIdx.x;
  const int lane = t & 63, w = t >> 6;
  const int wr = w >> 2, wc = w & 3;
  const int l15 = lane & 15, l4 = lane >> 4;

  const int flat = blockIdx.x;
  const int swz = (flat & 7) * 32 + (flat >> 3);
  const int bxt = swz & 15, byt = swz >> 4;
  const int row0 = byt * 128, col0 = bxt * 256;

  auto stageA = [&](int buf, int half, int tile) {
    const int o = t * 16;
    const int ridx = o >> 7;
    const int slot = (o >> 4) & 7;
    const int gr = (ridx >> 5) * 64 + half * 32 + (ridx & 31);
    gload_lds16(A + (size_t)(row0 + gr) * 4096 + (tile << 6) + ((slot ^ (ridx & 7)) << 3),
                (char*)&As[buf][half][0] + o);
  };
  auto stageB = [&](int buf, int half, int tile) {
#pragma unroll
    for (int g = 0; g < 2; ++g) {
      const int o = (g * 512 + t) * 16;
      const int ridx = o >> 7;
      const int slot = (o >> 4) & 7;
      const int gn = (ridx >> 5) * 64 + half * 32 + (ridx & 31);
      gload_lds16(B + (size_t)(col0 + gn) * 4096 + (tile << 6) + ((slot ^ (ridx & 7)) << 3),
                  (char*)&Bs[buf][half][0] + o);
    }
  };

  bf16x8 af[2][2], bf0[2][2], bf1[2][2];
  auto loadA = [&](int buf, int half) {
#pragma unroll
    for (int f = 0; f < 2; ++f)
#pragma unroll
      for (int ks = 0; ks < 2; ++ks) {
        const int idx = wr * 32 + f * 16 + l15;
        const int slot = ks * 4 + l4;
        af[f][ks] = *(const bf16x8*)((const char*)&As[buf][half][0] + idx * 128 +
                                     ((slot ^ (idx & 7)) << 4));
      }
  };
  auto loadB = [&](int buf, int half, bf16x8 (&dst)[2][2]) {
#pragma unroll
    for (int e = 0; e < 2; ++e)
#pragma unroll
      for (int ks = 0; ks < 2; ++ks) {
        const int idx = wc * 32 + e * 16 + l15;
        const int slot = ks * 4 + l4;
        dst[e][ks] = *(const bf16x8*)((const char*)&Bs[buf][half][0] + idx * 128 +
                                      ((slot ^ (idx & 7)) << 4));
      }
  };

  f32x4 acc[4][4];
#pragma unroll
  for (int m_ = 0; m_ < 4; ++m_)
#pragma unroll
    for (int n_ = 0; n_ < 4; ++n_) acc[m_][n_] = f32x4{0.f, 0.f, 0.f, 0.f};

  const int nit = (4096 >> 6) >> 1;

  stageA(0, 0, 0); stageA(0, 1, 0); stageB(0, 0, 0); stageB(0, 1, 0);
  stageA(1, 0, 1); stageB(1, 1, 1);
  VMW(3);
  BAR;

  for (int i = 0; i < nit; ++i) {
    const int tb = 2 * i;
    const bool g2 = (i + 1 < nit);
    loadA(0, 0); loadB(0, 0, bf0);
    stageA(1, 1, tb + 1);
    BAR; PRIO1; mfq16<0, 0>(acc, af, bf0); PRIO0; BAR;
    loadB(0, 1, bf1);
    stageB(1, 0, tb + 1);
    BAR; PRIO1; mfq16<0, 1>(acc, af, bf1); PRIO0; BAR;
    loadA(0, 1);
    if (g2) stageA(0, 0, tb + 2);
    BAR; PRIO1; mfq16<1, 1>(acc, af, bf1); PRIO0; BAR;
    if (g2) stageB(0, 1, tb + 2);
    BAR; PRIO1; mfq16<1, 0>(acc, af, bf0); PRIO0;
    if (g2) { VMW(3); } else { VMW(0); }
    BAR;
    loadA(1, 0); loadB(1, 0, bf0);
    if (g2) stageA(0, 1, tb + 2);
    BAR; PRIO1; mfq16<0, 0>(acc, af, bf0); PRIO0; BAR;
    loadB(1, 1, bf1);
    if (g2) stageB(0, 0, tb + 2);
    BAR; PRIO1; mfq16<0, 1>(acc, af, bf1); PRIO0; BAR;
    loadA(1, 1);
    if (g2) stageA(1, 0, tb + 3);
    BAR; PRIO1; mfq16<1, 1>(acc, af, bf1); PRIO0; BAR;
    if (g2) stageB(1, 1, tb + 3);
    BAR; PRIO1; mfq16<1, 0>(acc, af, bf0); PRIO0;
    if (g2) { VMW(3); } else { VMW(0); }
    BAR;
  }

#pragma unroll
  for (int am = 0; am < 4; ++am) {
    const int rowb = row0 + wr * 64 + (am >> 1) * 32 + (am & 1) * 16 + l4 * 4;
#pragma unroll
    for (int an = 0; an < 4; ++an) {
      const int colb = col0 + wc * 64 + (an >> 1) * 32 + (an & 1) * 16 + l15;
#pragma unroll
      for (int r = 0; r < 4; ++r)
        C[(size_t)(rowb + r) * 4096 + colb] = acc[am][an][r];
    }
  }
}

// ---------------- attention staging: K tile [64][128] + V^T tile [128][64], swizzled ----------------
__device__ __forceinline__ void stage_kv(const u16* __restrict__ k, const u16* __restrict__ vt,
                                         const int kvh, const int kv0, u16* KsB, u16* VsB,
                                         const int t) {
#pragma unroll
  for (int i = 0; i < 4; ++i) {
    const int o = (i * 256 + t) * 16;
    const int row = o >> 8;
    const int slot = (o >> 4) & 15;
    gload_lds16(k + (size_t)(kv0 + row) * (NKVH * HD) + kvh * HD + ((slot ^ (row & 7)) << 3),
                (char*)KsB + o);
  }
#pragma unroll
  for (int i = 0; i < 4; ++i) {
    const int o = (i * 256 + t) * 16;
    const int row = o >> 7;
    const int slot = (o >> 4) & 7;
    gload_lds16(vt + (size_t)(kvh * HD + row) * SEQ + kv0 + ((slot ^ (row & 7)) << 3),
                (char*)VsB + o);
  }
}

// ---------------- causal GQA flash attention, swapped-QK in-register softmax ----------------
__global__ void __launch_bounds__(256) attn_fwd(const u16* __restrict__ q, const u16* __restrict__ k,
                                                const u16* __restrict__ vt, u16* __restrict__ ctx) {
  __shared__ u16 Ks[2][64 * 128];
  __shared__ u16 Vs[2][128 * 64];
  const int t = threadIdx.x, lane = t & 63, w = t >> 6;
  const int h = blockIdx.x;
  const int qb = (int)gridDim.y - 1 - (int)blockIdx.y;
  const int kvh = h >> 2;
  const int q0 = qb * 64;
  const int sq_base = q0 + w * 16;
  const int l15 = lane & 15, l4 = lane >> 4;
  const int sq_abs = sq_base + l15;

  bf16x8 qf[4];
  {
    const u16* qp = q + (size_t)sq_abs * (NHEADS * HD) + h * HD + l4 * 8;
#pragma unroll
    for (int kb = 0; kb < 4; ++kb) qf[kb] = *(const bf16x8*)(qp + kb * 32);
  }
  f32x4 po[8];
#pragma unroll
  for (int i = 0; i < 8; ++i) po[i] = f32x4{0.f, 0.f, 0.f, 0.f};
  float mrow = -1e30f;
  float lrow = 0.f;

  const int nb = qb + 1;
  stage_kv(k, vt, kvh, 0, Ks[0], Vs[0], t);
  __syncthreads();
  int cur = 0;

  for (int b = 0; b < nb; ++b) {
    if (b + 1 < nb) stage_kv(k, vt, kvh, (b + 1) * 64, Ks[cur ^ 1], Vs[cur ^ 1], t);

    f32x4 st[4];
#pragma unroll
    for (int c = 0; c < 4; ++c) st[c] = f32x4{0.f, 0.f, 0.f, 0.f};
#pragma unroll
    for (int c = 0; c < 4; ++c) {
      const int row = c * 16 + l15;
#pragma unroll
      for (int kb = 0; kb < 4; ++kb) {
        const int slot = kb * 4 + l4;
        bf16x8 bk = *(const bf16x8*)((const char*)Ks[cur] + row * 256 + ((slot ^ (row & 7)) << 4));
        st[c] = __builtin_amdgcn_mfma_f32_16x16x32_bf16(bk, qf[kb], st[c], 0, 0, 0);
      }
    }

    if (b == nb - 1) {
#pragma unroll
      for (int c = 0; c < 4; ++c)
#pragma unroll
        for (int r = 0; r < 4; ++r) {
          const int sk = b * 64 + c * 16 + l4 * 4 + r;
          if (sk > sq_abs) st[c][r] = -1e30f;
        }
    }

    float rmax = -3e38f;
#pragma unroll
    for (int c = 0; c < 4; ++c)
      rmax = fmaxf(rmax, fmaxf(fmaxf(st[c][0], st[c][1]), fmaxf(st[c][2], st[c][3])));
    rmax = fmaxf(rmax, __shfl_xor(rmax, 16, 64));
    rmax = fmaxf(rmax, __shfl_xor(rmax, 32, 64));

    const bool skip = __all(rmax <= mrow + 8.f);
    const float mnew = skip ? mrow : fmaxf(mrow, rmax);

    float rs = 0.f;
#pragma unroll
    for (int c = 0; c < 4; ++c) {
      const float e0 = exp2f(st[c][0] - mnew), e1 = exp2f(st[c][1] - mnew);
      const float e2 = exp2f(st[c][2] - mnew), e3 = exp2f(st[c][3] - mnew);
      st[c][0] = e0; st[c][1] = e1; st[c][2] = e2; st[c][3] = e3;
      rs += (e0 + e1) + (e2 + e3);
    }
    rs += __shfl_xor(rs, 16, 64);
    rs += __shfl_xor(rs, 32, 64);

    if (!skip) {
      const float alpha = exp2f(mrow - mnew);
      mrow = mnew;
      lrow = lrow * alpha + rs;
      float av[4];
#pragma unroll
      for (int r = 0; r < 4; ++r) av[r] = __shfl(alpha, l4 * 4 + r, 16);
#pragma unroll
      for (int db = 0; db < 8; ++db)
#pragma unroll
        for (int r = 0; r < 4; ++r) po[db][r] *= av[r];
    } else {
      lrow += rs;
    }

    u32 pk[4][2];
#pragma unroll
    for (int c = 0; c < 4; ++c) {
      pk[c][0] = (u32)f2bf(st[c][0]) | ((u32)f2bf(st[c][1]) << 16);
      pk[c][1] = (u32)f2bf(st[c][2]) | ((u32)f2bf(st[c][3]) << 16);
    }
    const int src01 = l15 + ((lane & 16) << 1);
    const int src23 = src01 + 16;
    const bool lo = (lane & 32) == 0;
#pragma unroll
    for (int kb2 = 0; kb2 < 2; ++kb2) {
      const int c0 = kb2 * 2, c1 = c0 + 1;
      const u32 a0 = (u32)__shfl((int)pk[c0][0], src01, 64);
      const u32 a1 = (u32)__shfl((int)pk[c0][1], src01, 64);
      const u32 a2 = (u32)__shfl((int)pk[c0][0], src23, 64);
      const u32 a3 = (u32)__shfl((int)pk[c0][1], src23, 64);
      const u32 b0 = (u32)__shfl((int)pk[c1][0], src01, 64);
      const u32 b1 = (u32)__shfl((int)pk[c1][1], src01, 64);
      const u32 b2 = (u32)__shfl((int)pk[c1][0], src23, 64);
      const u32 b3 = (u32)__shfl((int)pk[c1][1], src23, 64);
      u32x4 wq;
      wq.x = lo ? a0 : b0;
      wq.y = lo ? a1 : b1;
      wq.z = lo ? a2 : b2;
      wq.w = lo ? a3 : b3;
      const bf16x8 pa = __builtin_bit_cast(bf16x8, wq);
#pragma unroll
      for (int db = 0; db < 8; ++db) {
        const int vrow = db * 16 + l15;
        const int pslot = kb2 * 4 + l4;
        bf16x8 bv = *(const bf16x8*)((const char*)Vs[cur] + vrow * 128 + ((pslot ^ (vrow & 7)) << 4));
        po[db] = __builtin_amdgcn_mfma_f32_16x16x32_bf16(pa, bv, po[db], 0, 0, 0);
      }
    }
    __syncthreads();
    cur ^= 1;
  }

  float rl[4];
#pragma unroll
  for (int r = 0; r < 4; ++r) rl[r] = 1.f / __shfl(lrow, l4 * 4 + r, 16);
#pragma unroll
  for (int db = 0; db < 8; ++db)
#pragma unroll
    for (int r = 0; r < 4; ++r) {
      const int sq = sq_base + l4 * 4 + r;
      const int d = db * 16 + l15;
      ctx[(size_t)sq * (NHEADS * HD) + h * HD + d] = f2bf(po[db][r] * rl[r]);
    }
}

extern "C" void kernel_launch(void* const* d_in, const int* in_sizes, int n_in,
                              void* d_out, int out_size, void* d_ws, size_t ws_size,
                              hipStream_t stream) {
  const float* hs = (const float*)d_in[0];
  const int* pos = (const int*)d_in[1];
  const float* Wq = (const float*)d_in[2];
  const float* Wk = (const float*)d_in[3];
  const float* Wv = (const float*)d_in[4];
  const float* Wo = (const float*)d_in[5];

  u16* ws = (u16*)d_ws;
  u16* Xb = ws;                                   // [2048][4096]
  u16* Wqt = Xb + (size_t)2048 * 4096;            // [4096][4096]
  u16* Wkt = Wqt + (size_t)4096 * 4096;           // [1024][4096]
  u16* Wvt = Wkt + (size_t)1024 * 4096;           // [1024][4096]
  u16* Wot = Wvt + (size_t)1024 * 4096;           // [4096][4096]
  u16* qb = Wot + (size_t)4096 * 4096;            // [2048][4096]
  u16* kb = qb + (size_t)2048 * 4096;             // [2048][1024]
  u16* vb = kb + (size_t)2048 * 1024;             // [2048][1024]
  u16* vtb = vb + (size_t)2048 * 1024;            // [1024][2048]
  u16* ctx = vtb + (size_t)1024 * 2048;           // [2048][4096]
  const size_t need = ((size_t)(ctx - ws) + (size_t)2048 * 4096) * 2;
  if (ws_size < need) return;

  conv_f2b_vec<<<8192, 256, 0, stream>>>(hs, Xb, 2048 * 4096);
  trans_f2b<<<dim3(128, 128), 256, 0, stream>>>(Wq, Wqt, 4096, 4096);
  trans_f2b<<<dim3(32, 128), 256, 0, stream>>>(Wk, Wkt, 4096, 1024);
  trans_f2b<<<dim3(32, 128), 256, 0, stream>>>(Wv, Wvt, 4096, 1024);

  // fused Q+K+V projections (192 gemm blocks) + folded Wo transpose (64 blocks)
  gemm8p32<<<256, 512, 0, stream>>>(Xb, Wqt, Wkt, Wvt, qb, kb, vb, Wo, Wot);

  const float qscale = 0.08838834764831845f * 1.44269504088896340f;  // 1/sqrt(128)*log2(e)
  rope_ip<<<16384, 256, 0, stream>>>(qb, pos, 5, qscale);
  rope_ip<<<4096, 256, 0, stream>>>(kb, pos, 3, 1.0f);

  trans_b2b<<<dim3(32, 64), 256, 0, stream>>>(vb, vtb, 2048, 1024);

  attn_fwd<<<dim3(32, 32), 256, 0, stream>>>(qb, kb, vtb, ctx);

  // output projection -> fp32 d_out
  gemm8p16<<<256, 512, 0, stream>>>(ctx, Wot, (float*)d_out);
}